// Round 6
// baseline (544.901 us; speedup 1.0000x reference)
//
#include <hip/hip_runtime.h>
#include <math.h>

#define TEMP 0.0005f
#define B_    32
#define CMEL  80
#define CTXT  512
#define T1_   1600
#define T2_   400

typedef short short8 __attribute__((ext_vector_type(8)));
typedef float f32x4 __attribute__((ext_vector_type(4)));

__device__ inline unsigned short f2bf(float f) {
    unsigned u = __float_as_uint(f);
    u += 0x7FFF + ((u >> 16) & 1);
    return (unsigned short)(u >> 16);
}
__device__ inline unsigned pack2(float a, float b) {
    return (unsigned)f2bf(a) | ((unsigned)f2bf(b) << 16);
}
__device__ inline float bf2f(unsigned short v) { return __uint_as_float(((unsigned)v) << 16); }

// async global->LDS, 16B per lane. Dest must be wave-uniform base + lane*16 (linear).
__device__ __forceinline__ void gl_lds16(const unsigned short* g, short* l) {
    __builtin_amdgcn_global_load_lds(
        (const __attribute__((address_space(1))) unsigned int*)g,
        (__attribute__((address_space(3))) unsigned int*)l,
        16, 0, 0);
}

// ---------------- merged: speaker-embed bias vectors + all weight casts ----------------
// blocks [0,74): bias dot-products; blocks [74,6798): weight casts.
__global__ void prep_kernel(const float* __restrict__ se,
                            const float* __restrict__ Wks, const float* __restrict__ bks,
                            const float* __restrict__ Wqs, const float* __restrict__ bqs,
                            float* __restrict__ kb, float* __restrict__ qb,
                            const float* __restrict__ Wk1, const float* __restrict__ Wk2,
                            const float* __restrict__ Wq1, const float* __restrict__ Wq2,
                            const float* __restrict__ Wq3,
                            unsigned short* __restrict__ Ab1, unsigned short* __restrict__ A2,
                            unsigned short* __restrict__ A3, unsigned short* __restrict__ A4,
                            unsigned short* __restrict__ A5) {
    if (blockIdx.x < 74) {
        int tid = blockIdx.x * blockDim.x + threadIdx.x;
        const int nk = B_ * CTXT;
        if (tid < nk) {
            int b = tid / CTXT, c = tid % CTXT;
            const float4* s4 = reinterpret_cast<const float4*>(se + b * CTXT);
            const float4* w4 = reinterpret_cast<const float4*>(Wks + (size_t)c * CTXT);
            float acc = bks[c];
            #pragma unroll 4
            for (int j = 0; j < CTXT / 4; ++j) {
                float4 a = s4[j], w = w4[j];
                acc += a.x * w.x + a.y * w.y + a.z * w.z + a.w * w.w;
            }
            kb[tid] = acc;
        } else if (tid < nk + B_ * CMEL) {
            int t = tid - nk;
            int b = t / CMEL, c = t % CMEL;
            const float4* s4 = reinterpret_cast<const float4*>(se + b * CTXT);
            const float4* w4 = reinterpret_cast<const float4*>(Wqs + (size_t)c * CTXT);
            float acc = bqs[c];
            #pragma unroll 4
            for (int j = 0; j < CTXT / 4; ++j) {
                float4 a = s4[j], w = w4[j];
                acc += a.x * w.x + a.y * w.y + a.z * w.z + a.w * w.w;
            }
            qb[t] = acc;
        }
        return;
    }
    int e = (blockIdx.x - 74) * 256 + threadIdx.x;
    const int n1 = 1572864, n2 = 81920, n3 = 46080, n4 = 12800, n5 = 7680;
    if (e < n1) {
        int co = e / 1536, rem = e - co * 1536;
        int dt = rem >> 9, ci = rem & 511;
        Ab1[e] = f2bf(Wk1[((size_t)co * 512 + ci) * 3 + dt]);
    } else if ((e -= n1) < n2) {
        A2[e] = f2bf(Wk2[e]);
    } else if ((e -= n2) < n3) {
        int co = e / 288, rem = e - co * 288;
        int dt = rem / 96, cc = rem - dt * 96;
        A3[e] = (cc < 80) ? f2bf(Wq1[((size_t)co * 80 + cc) * 3 + dt]) : 0;
    } else if ((e -= n3) < n4) {
        A4[e] = f2bf(Wq2[e]);
    } else if ((e -= n4) < n5) {
        int co = e / 96, cc = e - co * 96;
        A5[e] = (cc < 80) ? f2bf(Wq3[co * 80 + cc]) : 0;
    }
}

// ---------------- cast keys+bias -> Xk[b][t+1][512] bf16 (transposed, padded rows) ----
__global__ void castXk_kernel(const float* __restrict__ keys, const float* __restrict__ kb,
                              unsigned short* __restrict__ Xt) {
    __shared__ float tile[64][65];
    const int b = blockIdx.z;
    const int row0 = blockIdx.x * 64;
    const int ci0 = blockIdx.y * 64;
    const int tid = threadIdx.x;
    #pragma unroll
    for (int i = 0; i < 16; ++i) {
        int linear = i * 256 + tid;
        int ci_l = linear >> 6, t_l = linear & 63;
        int t = row0 + t_l - 1;
        float v = 0.f;
        if (t >= 0 && t < 400)
            v = keys[((size_t)b * 512 + ci0 + ci_l) * 400 + t] + kb[b * 512 + ci0 + ci_l];
        tile[t_l][ci_l] = v;
    }
    __syncthreads();
    #pragma unroll
    for (int i = 0; i < 16; ++i) {
        int linear = i * 256 + tid;
        int t_l = linear >> 6, ci_l = linear & 63;
        int row = row0 + t_l;
        if (row < 456)
            Xt[((size_t)b * 456 + row) * 512 + ci0 + ci_l] = f2bf(tile[t_l][ci_l]);
    }
}

// ---------------- cast queries+bias -> Xq1[b][t+1][96] bf16 (transposed, halo+ch pad) ----
__global__ __launch_bounds__(256) void castXq_kernel(
        const float* __restrict__ q, const float* __restrict__ qb,
        unsigned short* __restrict__ Xq1) {
    __shared__ float tile[80][65];
    const int b = blockIdx.y;
    const int t0 = blockIdx.x * 64;
    const int tid = threadIdx.x;
    if (t0 == 0 && tid < 48)
        ((unsigned*)(Xq1 + (size_t)b * 1602 * 96))[tid] = 0u;
    if (t0 == 1536 && tid < 48)
        ((unsigned*)(Xq1 + ((size_t)b * 1602 + 1601) * 96))[tid] = 0u;
    {
        int tl = tid & 63, c0 = tid >> 6;
        for (int c = c0; c < 80; c += 4)
            tile[c][tl] = q[((size_t)b * 80 + c) * 1600 + t0 + tl] + qb[b * 80 + c];
    }
    __syncthreads();
    int row = tid >> 2, cg = tid & 3;
    int t = t0 + row;
    unsigned* orow = (unsigned*)(Xq1 + ((size_t)b * 1602 + t + 1) * 96 + cg * 24);
    #pragma unroll
    for (int jj = 0; jj < 12; ++jj) {
        int c0 = cg * 24 + jj * 2, c1 = c0 + 1;
        float f0 = (c0 < 80) ? tile[c0][row] : 0.f;
        float f1 = (c1 < 80) ? tile[c1][row] : 0.f;
        orow[jj] = pack2(f0, f1);
    }
}

// ---------------- keys conv1 via bf16 MFMA -> channel-last k1c[b][t][1024] ----------------
// Staging via global_load_lds (width 16): no VGPR round-trip, no ds_write, linear LDS dest.
// LDS re-blocked k-slot-major (As[dt][c16][128][8], Xs[c16][66][8]) so MFMA fragment reads
// are 16 contiguous 16B lanes per quad: each 8-lane phase covers all 32 banks exactly once
// (conflict-free, no pad). The layout permutation lives in the per-lane GLOBAL src address
// (pre-swizzled-source pattern); LDS dest stays wave-linear as the HW requires.
__global__ __launch_bounds__(256) void conv1k_mfma(
        const unsigned short* __restrict__ Ab, const unsigned short* __restrict__ Xt,
        const float* __restrict__ bias, unsigned short* __restrict__ k1c) {
    __shared__ short As[3 * 4 * 128 * 8];   // [dt][c16][r][8]  = 24576 B, linear
    __shared__ short Xs[4 * 66 * 8];        // [c16][row][8]    =  4224 B, linear
    const int b = blockIdx.z;
    const int co0 = blockIdx.y * 128;
    const int t0 = blockIdx.x * 64;
    const int tid = threadIdx.x;
    const int lane = tid & 63, w = tid >> 6;
    const int wm = w >> 1, wn = w & 1;
    const int l15 = lane & 15, quad = lane >> 4;
    f32x4 acc[4][2];
    #pragma unroll
    for (int mt = 0; mt < 4; ++mt)
        #pragma unroll
        for (int nt = 0; nt < 2; ++nt)
            acc[mt][nt] = (f32x4){0.f, 0.f, 0.f, 0.f};

    // per-thread staging coords (compile-time unrolled, all scalar ALU)
    const int xc16 = tid / 66, xrow = tid - xc16 * 66;       // Xs call 1: e = tid

    for (int ci0 = 0; ci0 < 512; ci0 += 32) {
        __syncthreads();
        // As: 6 x 256-lane calls; element e = i*256+tid -> [dt][c16][r]
        #pragma unroll
        for (int i = 0; i < 6; ++i) {
            int e = i * 256 + tid;
            int dt = e >> 9, c16 = (e >> 7) & 3, r = e & 127;
            gl_lds16(Ab + (size_t)(co0 + r) * 1536 + dt * 512 + ci0 + c16 * 8,
                     As + (size_t)(i * 256 + w * 64) * 8);
        }
        // Xs: e = tid (0..255) then masked tail e = 256..263 (c16 = 3, row 58..65)
        gl_lds16(Xt + ((size_t)b * 456 + t0 + xrow) * 512 + ci0 + xc16 * 8,
                 Xs + (size_t)(w * 64) * 8);
        if (tid < 8) {
            int row = 58 + tid;
            gl_lds16(Xt + ((size_t)b * 456 + t0 + row) * 512 + ci0 + 3 * 8,
                     Xs + (size_t)256 * 8);
        }
        __syncthreads();   // compiler drains vmcnt(0) here -> LDS valid
        #pragma unroll
        for (int dt = 0; dt < 3; ++dt) {
            short8 af[4], bfr[2];
            #pragma unroll
            for (int mt = 0; mt < 4; ++mt)
                af[mt] = *(const short8*)(As + (size_t)((dt * 4 + quad) * 128 + wm * 64 + mt * 16 + l15) * 8);
            #pragma unroll
            for (int nt = 0; nt < 2; ++nt)
                bfr[nt] = *(const short8*)(Xs + (size_t)(quad * 66 + wn * 32 + nt * 16 + l15 + dt) * 8);
            #pragma unroll
            for (int mt = 0; mt < 4; ++mt)
                #pragma unroll
                for (int nt = 0; nt < 2; ++nt)
                    acc[mt][nt] = __builtin_amdgcn_mfma_f32_16x16x32_bf16(af[mt], bfr[nt], acc[mt][nt], 0, 0, 0);
        }
    }
    #pragma unroll
    for (int mt = 0; mt < 4; ++mt) {
        int cob = co0 + wm * 64 + mt * 16 + quad * 4;
        float bv[4];
        #pragma unroll
        for (int r = 0; r < 4; ++r) bv[r] = bias[cob + r];
        #pragma unroll
        for (int nt = 0; nt < 2; ++nt) {
            int t = t0 + wn * 32 + nt * 16 + l15;
            if (t >= 400) continue;
            float v0 = fmaxf(acc[mt][nt][0] + bv[0], 0.f);
            float v1 = fmaxf(acc[mt][nt][1] + bv[1], 0.f);
            float v2 = fmaxf(acc[mt][nt][2] + bv[2], 0.f);
            float v3 = fmaxf(acc[mt][nt][3] + bv[3], 0.f);
            uint2 p;
            p.x = pack2(v0, v1);
            p.y = pack2(v2, v3);
            *(uint2*)(k1c + ((size_t)b * 400 + t) * 1024 + cob) = p;
        }
    }
}

// ---------------- k2 GEMM with K split across 4 waves (800 blocks) ----------------
__global__ __launch_bounds__(256) void gemm_k2_kernel(
        const unsigned short* __restrict__ A, const unsigned short* __restrict__ X,
        const float* __restrict__ bias, unsigned short* __restrict__ out) {
    __shared__ float red[3][64][21];
    const int b = blockIdx.y;
    const int tid = threadIdx.x, lane = tid & 63, w = tid >> 6;
    const int l15 = lane & 15, quad = lane >> 4;
    const int s = blockIdx.x * 16 + l15;          // 25*16 = 400, always valid
    const unsigned short* xb = X + ((size_t)b * 400 + s) * 1024 + quad * 8;
    f32x4 acc[5];
    #pragma unroll
    for (int mt = 0; mt < 5; ++mt) acc[mt] = (f32x4){0.f, 0.f, 0.f, 0.f};
    #pragma unroll
    for (int kk = 0; kk < 8; ++kk) {
        int kc = w * 8 + kk;
        short8 bfr = *(const short8*)(xb + kc * 32);
        #pragma unroll
        for (int mt = 0; mt < 5; ++mt) {
            short8 af = *(const short8*)(A + (size_t)(mt * 16 + l15) * 1024 + kc * 32 + quad * 8);
            acc[mt] = __builtin_amdgcn_mfma_f32_16x16x32_bf16(af, bfr, acc[mt], 0, 0, 0);
        }
    }
    if (w > 0) {
        #pragma unroll
        for (int mt = 0; mt < 5; ++mt)
            #pragma unroll
            for (int r = 0; r < 4; ++r)
                red[w - 1][lane][mt * 4 + r] = acc[mt][r];
    }
    __syncthreads();
    if (w != 0) return;
    #pragma unroll
    for (int wv = 0; wv < 3; ++wv)
        #pragma unroll
        for (int mt = 0; mt < 5; ++mt)
            #pragma unroll
            for (int r = 0; r < 4; ++r)
                acc[mt][r] += red[wv][lane][mt * 4 + r];
    float v[5][4];
    float ss = 0.f;
    #pragma unroll
    for (int mt = 0; mt < 5; ++mt)
        #pragma unroll
        for (int r = 0; r < 4; ++r) {
            float x = acc[mt][r] + bias[mt * 16 + quad * 4 + r];
            v[mt][r] = x;
            ss += x * x;
        }
    ss += __shfl_xor(ss, 16, 64);
    ss += __shfl_xor(ss, 32, 64);
    unsigned short* orow = out + ((size_t)b * 400 + s) * 96;
    #pragma unroll
    for (int mt = 0; mt < 5; ++mt) {
        uint2 p;
        p.x = pack2(v[mt][0], v[mt][1]);
        p.y = pack2(v[mt][2], v[mt][3]);
        *(uint2*)(orow + mt * 16 + quad * 4) = p;
    }
    if (quad == 0) {
        uint4 z0 = {pack2(-0.5f * ss, 1.0f), 0u, 0u, 0u};
        uint4 z1 = {0u, 0u, 0u, 0u};
        *(uint4*)(orow + 80) = z0;
        *(uint4*)(orow + 88) = z1;
    }
}

// ---------------- fused q-path: k3-conv(relu) -> 1x1(relu) -> 1x1 + q2 epilogue --------
// Wave-private chaining: stages chain through LDS with NO barriers (rows are wave-private).
__global__ __launch_bounds__(256) void qpath_fused(
        const unsigned short* __restrict__ A3, const unsigned short* __restrict__ A4,
        const unsigned short* __restrict__ A5, const unsigned short* __restrict__ Xq1,
        const float* __restrict__ bq1, const float* __restrict__ bq2,
        const float* __restrict__ bq3, unsigned short* __restrict__ qT) {
    __shared__ short LA[64 * 168];   // stage-1 out: [t_local][160ch] (pad 168)
    __shared__ short LB[64 * 104];   // stage-2 out: [t_local][96ch]  (pad 104)
    const int b = blockIdx.y;
    const int t0 = blockIdx.x * 64;
    const int tid = threadIdx.x;
    const int lane = tid & 63, w = tid >> 6;
    const int l15 = lane & 15, quad = lane >> 4;
    const int row = w * 16 + l15;          // wave-private local t row
    const int s = t0 + row;                // global t row, always < 1600
    const unsigned short* xb = Xq1 + (size_t)b * 1602 * 96;

    // ---- stage 1 (q1): relu(conv3) -> LA; K = 288 (3 dt x 96 ch), M = 160 ----
    {
        f32x4 acc[10];
        #pragma unroll
        for (int mt = 0; mt < 10; ++mt) acc[mt] = (f32x4){0.f, 0.f, 0.f, 0.f};
        #pragma unroll
        for (int kc = 0; kc < 9; ++kc) {
            const int dt = kc / 3, koff = (kc - dt * 3) * 32;
            short8 bfr = *(const short8*)(xb + (size_t)(s + dt) * 96 + koff + quad * 8);
            #pragma unroll
            for (int mt = 0; mt < 10; ++mt) {
                short8 af = *(const short8*)(A3 + (size_t)(mt * 16 + l15) * 288 + kc * 32 + quad * 8);
                acc[mt] = __builtin_amdgcn_mfma_f32_16x16x32_bf16(af, bfr, acc[mt], 0, 0, 0);
            }
        }
        #pragma unroll
        for (int mt = 0; mt < 10; ++mt) {
            float x0 = fmaxf(acc[mt][0] + bq1[mt * 16 + quad * 4 + 0], 0.f);
            float x1 = fmaxf(acc[mt][1] + bq1[mt * 16 + quad * 4 + 1], 0.f);
            float x2 = fmaxf(acc[mt][2] + bq1[mt * 16 + quad * 4 + 2], 0.f);
            float x3 = fmaxf(acc[mt][3] + bq1[mt * 16 + quad * 4 + 3], 0.f);
            uint2 p;
            p.x = pack2(x0, x1);
            p.y = pack2(x2, x3);
            *(uint2*)(LA + row * 168 + mt * 16 + quad * 4) = p;
        }
    }

    // ---- stage 2 (q2): relu(1x1) -> LB; K = 160 (5 kc), M = 80 (+ zero pad to 96) ----
    {
        f32x4 acc[5];
        #pragma unroll
        for (int mt = 0; mt < 5; ++mt) acc[mt] = (f32x4){0.f, 0.f, 0.f, 0.f};
        #pragma unroll
        for (int kc = 0; kc < 5; ++kc) {
            short8 bfr = *(const short8*)(LA + row * 168 + kc * 32 + quad * 8);
            #pragma unroll
            for (int mt = 0; mt < 5; ++mt) {
                short8 af = *(const short8*)(A4 + (size_t)(mt * 16 + l15) * 160 + kc * 32 + quad * 8);
                acc[mt] = __builtin_amdgcn_mfma_f32_16x16x32_bf16(af, bfr, acc[mt], 0, 0, 0);
            }
        }
        #pragma unroll
        for (int mt = 0; mt < 5; ++mt) {
            float x0 = fmaxf(acc[mt][0] + bq2[mt * 16 + quad * 4 + 0], 0.f);
            float x1 = fmaxf(acc[mt][1] + bq2[mt * 16 + quad * 4 + 1], 0.f);
            float x2 = fmaxf(acc[mt][2] + bq2[mt * 16 + quad * 4 + 2], 0.f);
            float x3 = fmaxf(acc[mt][3] + bq2[mt * 16 + quad * 4 + 3], 0.f);
            uint2 p;
            p.x = pack2(x0, x1);
            p.y = pack2(x2, x3);
            *(uint2*)(LB + row * 104 + mt * 16 + quad * 4) = p;
        }
        uint2 z = {0u, 0u};
        *(uint2*)(LB + row * 104 + 80 + quad * 4) = z;   // ch 80..95 = 0 across quads
    }

    // ---- stage 3 (q3): 1x1, no relu; K = 96 (3 kc), M = 80; q2-epilogue to qT ----
    {
        f32x4 acc[5];
        #pragma unroll
        for (int mt = 0; mt < 5; ++mt) acc[mt] = (f32x4){0.f, 0.f, 0.f, 0.f};
        #pragma unroll
        for (int kc = 0; kc < 3; ++kc) {
            short8 bfr = *(const short8*)(LB + row * 104 + kc * 32 + quad * 8);
            #pragma unroll
            for (int mt = 0; mt < 5; ++mt) {
                short8 af = *(const short8*)(A5 + (size_t)(mt * 16 + l15) * 96 + kc * 32 + quad * 8);
                acc[mt] = __builtin_amdgcn_mfma_f32_16x16x32_bf16(af, bfr, acc[mt], 0, 0, 0);
            }
        }
        float v[5][4];
        float ss = 0.f;
        #pragma unroll
        for (int mt = 0; mt < 5; ++mt)
            #pragma unroll
            for (int r = 0; r < 4; ++r) {
                float x = acc[mt][r] + bq3[mt * 16 + quad * 4 + r];
                v[mt][r] = x;
                ss += x * x;
            }
        ss += __shfl_xor(ss, 16, 64);
        ss += __shfl_xor(ss, 32, 64);
        unsigned short* orow = qT + ((size_t)b * T1_ + s) * 96;
        #pragma unroll
        for (int mt = 0; mt < 5; ++mt) {
            uint2 p;
            p.x = pack2(v[mt][0], v[mt][1]);
            p.y = pack2(v[mt][2], v[mt][3]);
            *(uint2*)(orow + mt * 16 + quad * 4) = p;
        }
        if (quad == 0) {
            uint4 z0 = {pack2(1.0f, -0.5f * ss), 0u, 0u, 0u};
            uint4 z1 = {0u, 0u, 0u, 0u};
            *(uint4*)(orow + 80) = z0;
            *(uint4*)(orow + 88) = z1;
        }
    }
}

// ---------------- qk MFMA -> bf16 logits lgt[b][t1][s] ----------------
// Operand-swapped (round-5): lane owns t1 row; 25 x 8B stores/wave. Neutral vs round-4
// but strictly fewer instructions; kept.
__global__ __launch_bounds__(64) void attn_logits_kernel(
        const unsigned short* __restrict__ qT, const unsigned short* __restrict__ kT,
        unsigned short* __restrict__ lgt) {
    const int b = blockIdx.y;
    const int t10 = blockIdx.x * 16;
    const int lane = threadIdx.x;
    const int l15 = lane & 15, quad = lane >> 4;

    // B-operand: 16 q-rows (t1 = t10 + l15)
    const unsigned short* qrow = qT + ((size_t)b * T1_ + t10 + l15) * 96;
    short8 bq[3];
    #pragma unroll
    for (int kc = 0; kc < 3; ++kc)
        bq[kc] = *(const short8*)(qrow + kc * 32 + quad * 8);

    f32x4 acc[25];
    #pragma unroll
    for (int ns = 0; ns < 25; ++ns) acc[ns] = (f32x4){0.f, 0.f, 0.f, 0.f};
    // A-operand: s-rows (s = ns*16 + l15 for fragment load)
    const unsigned short* kbase = kT + (size_t)b * T2_ * 96 + l15 * 96 + quad * 8;
    #pragma unroll
    for (int ns = 0; ns < 25; ++ns) {
        #pragma unroll
        for (int kc = 0; kc < 3; ++kc) {
            short8 ak = *(const short8*)(kbase + ns * 16 * 96 + kc * 32);
            acc[ns] = __builtin_amdgcn_mfma_f32_16x16x32_bf16(ak, bq[kc], acc[ns], 0, 0, 0);
        }
    }
    const float K2T = 2.0f * TEMP;
    unsigned short* orow = lgt + ((size_t)b * T1_ + t10 + l15) * T2_;  // lane-owned t1 row
    #pragma unroll
    for (int ns = 0; ns < 25; ++ns) {
        uint2 p;
        p.x = pack2(K2T * acc[ns][0], K2T * acc[ns][1]);
        p.y = pack2(K2T * acc[ns][2], K2T * acc[ns][3]);
        *(uint2*)(orow + ns * 16 + quad * 4) = p;   // s = ns*16 + quad*4 + [0..3]
    }
}

// ---------------- streaming double-softmax: lgt+prior+mask -> attn, lp ----------------
// 4 waves / block, 1 row / wave. Fully coalesced; 51200 waves.
__global__ __launch_bounds__(256) void softmax_kernel(
        const unsigned short* __restrict__ lgt, const int* __restrict__ mask,
        const float* __restrict__ prior,
        float* __restrict__ attn_out, float* __restrict__ lp_out) {
    const int b = blockIdx.y;
    const int t1 = blockIdx.x * 4 + (threadIdx.x >> 6);
    const int lane = threadIdx.x & 63;
    const unsigned short* lrow = lgt + ((size_t)b * T1_ + t1) * T2_;
    const float* prow = prior + ((size_t)b * T1_ + t1) * T2_;
    const int* mrow = mask + b * T2_;

    float l[7], pe[7], kp[7];
    #pragma unroll
    for (int j = 0; j < 7; ++j) {
        int s = lane + 64 * j;
        bool v = (j < 6) || (lane < 16);
        l[j]  = v ? bf2f(lrow[s]) : -1e30f;
        pe[j] = v ? (prow[s] + 1e-8f) : 1.f;
        kp[j] = (v && !mrow[v ? s : 0]) ? 1.f : 0.f;
    }
    float m = l[0];
    #pragma unroll
    for (int j = 1; j < 7; ++j) m = fmaxf(m, l[j]);
    #pragma unroll
    for (int off = 1; off <= 32; off <<= 1) m = fmaxf(m, __shfl_xor(m, off, 64));
    float e1[7];
    float sum = 0.f;
    #pragma unroll
    for (int j = 0; j < 7; ++j) { float e = __expf(l[j] - m); e1[j] = e; sum += e; }
    #pragma unroll
    for (int off = 1; off <= 32; off <<= 1) sum += __shfl_xor(sum, off, 64);
    const float lse = m + __logf(sum);

    float u[7];
    float sum2 = 0.f;
    #pragma unroll
    for (int j = 0; j < 7; ++j) {
        float uu = e1[j] * pe[j] * kp[j];
        u[j] = uu;
        sum2 += uu;
    }
    #pragma unroll
    for (int off = 1; off <= 32; off <<= 1) sum2 += __shfl_xor(sum2, off, 64);
    const float inv = 1.f / sum2;

    float* lpr = lp_out + ((size_t)b * T1_ + t1) * T2_;
    float* atr = attn_out + ((size_t)b * T1_ + t1) * T2_;
    #pragma unroll
    for (int j = 0; j < 7; ++j) {
        int s = lane + 64 * j;
        bool v = (j < 6) || (lane < 16);
        if (v) {
            lpr[s] = l[j] - lse + __logf(pe[j]);
            atr[s] = u[j] * inv;
        }
    }
}

extern "C" void kernel_launch(void* const* d_in, const int* in_sizes, int n_in,
                              void* d_out, int out_size, void* d_ws, size_t ws_size,
                              hipStream_t stream) {
    const float* queries = (const float*)d_in[0];
    const float* keys    = (const float*)d_in[1];
    const int*   mask    = (const int*)d_in[2];
    const float* prior   = (const float*)d_in[3];
    const float* se      = (const float*)d_in[4];
    const float* Wk1 = (const float*)d_in[5];
    const float* bk1 = (const float*)d_in[6];
    const float* Wk2 = (const float*)d_in[7];
    const float* bk2 = (const float*)d_in[8];
    const float* Wq1 = (const float*)d_in[9];
    const float* bq1 = (const float*)d_in[10];
    const float* Wq2 = (const float*)d_in[11];
    const float* bq2 = (const float*)d_in[12];
    const float* Wq3 = (const float*)d_in[13];
    const float* bq3 = (const float*)d_in[14];
    const float* Wks = (const float*)d_in[15];
    const float* bks = (const float*)d_in[16];
    const float* Wqs = (const float*)d_in[17];
    const float* bqs = (const float*)d_in[18];

    // workspace (float units), peak 14,240,768 fl = 57.0 MB:
    // head: kb 0 | qb 16,384 | Ab1 18,944 | A2 805,376 | A3 846,336 | A4 869,376
    //       A5 875,776 | qT 879,616 | kT 3,337,216 | D = 3,951,616
    // keys: Xk @D (3,735,552) | k1c @D+3,735,552 (6,553,600)
    // q:    Xq1 @D (2,460,672)  [Xq2/Xq3 eliminated by qpath_fused]
    // attn: lgt @D (10,240,000 fl as bf16) overlays dead scratch
    float* ws = (float*)d_ws;
    float* kb = ws;
    float* qb = ws + 16384;
    unsigned short* Ab1 = (unsigned short*)(ws + 18944);
    unsigned short* A2  = (unsigned short*)(ws + 805376);
    unsigned short* A3  = (unsigned short*)(ws + 846336);
    unsigned short* A4  = (unsigned short*)(ws + 869376);
    unsigned short* A5  = (unsigned short*)(ws + 875776);
    unsigned short* qT  = (unsigned short*)(ws + 879616);
    unsigned short* kT  = (unsigned short*)(ws + 3337216);
    const size_t D = 3951616;
    unsigned short* Xk  = (unsigned short*)(ws + D);
    unsigned short* k1c = (unsigned short*)(ws + D + 3735552);
    unsigned short* Xq1 = (unsigned short*)(ws + D);
    unsigned short* lgt = (unsigned short*)(ws + D);

    float* attn_out = (float*)d_out;
    float* lp_out   = attn_out + (size_t)B_ * T1_ * T2_;

    prep_kernel<<<dim3(6798), dim3(256), 0, stream>>>(se, Wks, bks, Wqs, bqs, kb, qb,
                                                      Wk1, Wk2, Wq1, Wq2, Wq3,
                                                      Ab1, A2, A3, A4, A5);
    // keys path
    castXk_kernel<<<dim3(8, 8, 32), dim3(256), 0, stream>>>(keys, kb, Xk);
    conv1k_mfma<<<dim3(7, 8, 32), dim3(256), 0, stream>>>(Ab1, Xk, bk1, k1c);
    gemm_k2_kernel<<<dim3(25, 32), 256, 0, stream>>>(A2, k1c, bk2, kT);
    // query path (fused: q1 -> q2 -> q3 in one kernel, LDS-chained)
    castXq_kernel<<<dim3(25, 32), dim3(256), 0, stream>>>(queries, qb, Xq1);
    qpath_fused<<<dim3(25, 32), dim3(256), 0, stream>>>(A3, A4, A5, Xq1,
                                                        bq1, bq2, bq3, qT);
    // attention: MFMA logits (bf16) then streaming double-softmax
    attn_logits_kernel<<<dim3(100, 32), dim3(64), 0, stream>>>(qT, kT, lgt);
    softmax_kernel<<<dim3(400, 32), dim3(256), 0, stream>>>(lgt, mask, prior, attn_out, lp_out);
}

// Round 7
// 501.198 us; speedup vs baseline: 1.0872x; 1.0872x over previous
//
#include <hip/hip_runtime.h>
#include <math.h>

#define TEMP 0.0005f
#define B_    32
#define CMEL  80
#define CTXT  512
#define T1_   1600
#define T2_   400

typedef short short8 __attribute__((ext_vector_type(8)));
typedef float f32x4 __attribute__((ext_vector_type(4)));

__device__ inline unsigned short f2bf(float f) {
    unsigned u = __float_as_uint(f);
    u += 0x7FFF + ((u >> 16) & 1);
    return (unsigned short)(u >> 16);
}
__device__ inline unsigned pack2(float a, float b) {
    return (unsigned)f2bf(a) | ((unsigned)f2bf(b) << 16);
}
__device__ inline float bf2f(unsigned short v) { return __uint_as_float(((unsigned)v) << 16); }

// async global->LDS, 16B per lane. Dest is wave-uniform base; lane i lands at base+i*16.
__device__ __forceinline__ void gl_lds16(const unsigned short* g, short* l) {
    __builtin_amdgcn_global_load_lds(
        (const __attribute__((address_space(1))) unsigned int*)g,
        (__attribute__((address_space(3))) unsigned int*)l,
        16, 0, 0);
}

// ---------------- merged: speaker-embed bias vectors + all weight casts ----------------
// blocks [0,74): bias dot-products; blocks [74,6798): weight casts.
__global__ void prep_kernel(const float* __restrict__ se,
                            const float* __restrict__ Wks, const float* __restrict__ bks,
                            const float* __restrict__ Wqs, const float* __restrict__ bqs,
                            float* __restrict__ kb, float* __restrict__ qb,
                            const float* __restrict__ Wk1, const float* __restrict__ Wk2,
                            const float* __restrict__ Wq1, const float* __restrict__ Wq2,
                            const float* __restrict__ Wq3,
                            unsigned short* __restrict__ Ab1, unsigned short* __restrict__ A2,
                            unsigned short* __restrict__ A3, unsigned short* __restrict__ A4,
                            unsigned short* __restrict__ A5) {
    if (blockIdx.x < 74) {
        int tid = blockIdx.x * blockDim.x + threadIdx.x;
        const int nk = B_ * CTXT;
        if (tid < nk) {
            int b = tid / CTXT, c = tid % CTXT;
            const float4* s4 = reinterpret_cast<const float4*>(se + b * CTXT);
            const float4* w4 = reinterpret_cast<const float4*>(Wks + (size_t)c * CTXT);
            float acc = bks[c];
            #pragma unroll 4
            for (int j = 0; j < CTXT / 4; ++j) {
                float4 a = s4[j], w = w4[j];
                acc += a.x * w.x + a.y * w.y + a.z * w.z + a.w * w.w;
            }
            kb[tid] = acc;
        } else if (tid < nk + B_ * CMEL) {
            int t = tid - nk;
            int b = t / CMEL, c = t % CMEL;
            const float4* s4 = reinterpret_cast<const float4*>(se + b * CTXT);
            const float4* w4 = reinterpret_cast<const float4*>(Wqs + (size_t)c * CTXT);
            float acc = bqs[c];
            #pragma unroll 4
            for (int j = 0; j < CTXT / 4; ++j) {
                float4 a = s4[j], w = w4[j];
                acc += a.x * w.x + a.y * w.y + a.z * w.z + a.w * w.w;
            }
            qb[t] = acc;
        }
        return;
    }
    int e = (blockIdx.x - 74) * 256 + threadIdx.x;
    const int n1 = 1572864, n2 = 81920, n3 = 46080, n4 = 12800, n5 = 7680;
    if (e < n1) {
        int co = e / 1536, rem = e - co * 1536;
        int dt = rem >> 9, ci = rem & 511;
        Ab1[e] = f2bf(Wk1[((size_t)co * 512 + ci) * 3 + dt]);
    } else if ((e -= n1) < n2) {
        A2[e] = f2bf(Wk2[e]);
    } else if ((e -= n2) < n3) {
        int co = e / 288, rem = e - co * 288;
        int dt = rem / 96, cc = rem - dt * 96;
        A3[e] = (cc < 80) ? f2bf(Wq1[((size_t)co * 80 + cc) * 3 + dt]) : 0;
    } else if ((e -= n3) < n4) {
        A4[e] = f2bf(Wq2[e]);
    } else if ((e -= n4) < n5) {
        int co = e / 96, cc = e - co * 96;
        A5[e] = (cc < 80) ? f2bf(Wq3[co * 80 + cc]) : 0;
    }
}

// ---------------- cast keys+bias -> Xk[b][t+1][512] bf16 (transposed, padded rows) ----
__global__ void castXk_kernel(const float* __restrict__ keys, const float* __restrict__ kb,
                              unsigned short* __restrict__ Xt) {
    __shared__ float tile[64][65];
    const int b = blockIdx.z;
    const int row0 = blockIdx.x * 64;
    const int ci0 = blockIdx.y * 64;
    const int tid = threadIdx.x;
    #pragma unroll
    for (int i = 0; i < 16; ++i) {
        int linear = i * 256 + tid;
        int ci_l = linear >> 6, t_l = linear & 63;
        int t = row0 + t_l - 1;
        float v = 0.f;
        if (t >= 0 && t < 400)
            v = keys[((size_t)b * 512 + ci0 + ci_l) * 400 + t] + kb[b * 512 + ci0 + ci_l];
        tile[t_l][ci_l] = v;
    }
    __syncthreads();
    #pragma unroll
    for (int i = 0; i < 16; ++i) {
        int linear = i * 256 + tid;
        int t_l = linear >> 6, ci_l = linear & 63;
        int row = row0 + t_l;
        if (row < 456)
            Xt[((size_t)b * 456 + row) * 512 + ci0 + ci_l] = f2bf(tile[t_l][ci_l]);
    }
}

// ---------------- cast queries+bias -> Xq1[b][t+1][96] bf16 (transposed, halo+ch pad) ----
__global__ __launch_bounds__(256) void castXq_kernel(
        const float* __restrict__ q, const float* __restrict__ qb,
        unsigned short* __restrict__ Xq1) {
    __shared__ float tile[80][65];
    const int b = blockIdx.y;
    const int t0 = blockIdx.x * 64;
    const int tid = threadIdx.x;
    if (t0 == 0 && tid < 48)
        ((unsigned*)(Xq1 + (size_t)b * 1602 * 96))[tid] = 0u;
    if (t0 == 1536 && tid < 48)
        ((unsigned*)(Xq1 + ((size_t)b * 1602 + 1601) * 96))[tid] = 0u;
    {
        int tl = tid & 63, c0 = tid >> 6;
        for (int c = c0; c < 80; c += 4)
            tile[c][tl] = q[((size_t)b * 80 + c) * 1600 + t0 + tl] + qb[b * 80 + c];
    }
    __syncthreads();
    int row = tid >> 2, cg = tid & 3;
    int t = t0 + row;
    unsigned* orow = (unsigned*)(Xq1 + ((size_t)b * 1602 + t + 1) * 96 + cg * 24);
    #pragma unroll
    for (int jj = 0; jj < 12; ++jj) {
        int c0 = cg * 24 + jj * 2, c1 = c0 + 1;
        float f0 = (c0 < 80) ? tile[c0][row] : 0.f;
        float f1 = (c1 < 80) ? tile[c1][row] : 0.f;
        orow[jj] = pack2(f0, f1);
    }
}

// ---------------- keys conv1 via bf16 MFMA -> channel-last k1c[b][t][1024] ----------------
// gload_lds staging, round-6 FIXED: LDS layouts As[dt][r][c16][8], Xs[row][c16][8] make the
// per-lane GLOBAL addresses contiguous again (lanes 0-3 = 64B of one row; 16 x 64B segments
// per wave — identical to the proven register-staged pattern). Round-6's k-slot-major layout
// scattered the wave to 64 x 16B @ 3KB stride -> 4x transactions, latency-bound 126 us.
// MFMA reads: row-stride 32 shorts, quad picks c16; bank=(l15*16+quad*4)%32 -> 8 lanes per
// 4-bank group x 8 phases = 1KB minimum, conflict-free.
__global__ __launch_bounds__(256) void conv1k_mfma(
        const unsigned short* __restrict__ Ab, const unsigned short* __restrict__ Xt,
        const float* __restrict__ bias, unsigned short* __restrict__ k1c) {
    __shared__ short As[3 * 128 * 32];   // [dt][r][c16][8] = 24576 B, linear
    __shared__ short Xs[66 * 32];        // [row][c16][8]   =  4224 B, linear
    const int b = blockIdx.z;
    const int co0 = blockIdx.y * 128;
    const int t0 = blockIdx.x * 64;
    const int tid = threadIdx.x;
    const int lane = tid & 63, w = tid >> 6;
    const int wm = w >> 1, wn = w & 1;
    const int l15 = lane & 15, quad = lane >> 4;
    f32x4 acc[4][2];
    #pragma unroll
    for (int mt = 0; mt < 4; ++mt)
        #pragma unroll
        for (int nt = 0; nt < 2; ++nt)
            acc[mt][nt] = (f32x4){0.f, 0.f, 0.f, 0.f};

    // staging coords: e = i*256+tid -> dt = e>>9, r = (e>>2)&127, c16 = e&3
    const int sr = tid >> 2, sc16 = tid & 3;     // within-256 part (r advances every 4 lanes)

    for (int ci0 = 0; ci0 < 512; ci0 += 32) {
        __syncthreads();
        // As: 6 calls x 256 lanes; global: 4 lanes read 64B contiguous of row (co0+r)
        #pragma unroll
        for (int i = 0; i < 6; ++i) {
            int e0 = i * 256;
            int dt = e0 >> 9, r = ((e0 >> 2) & 127) + sr;  // e0 multiple of 256: r-base + sr
            gl_lds16(Ab + (size_t)(co0 + (r & 127)) * 1536 + ((e0 + tid) >> 9) * 512 + ci0 + sc16 * 8,
                     As + (size_t)(e0 + w * 64) * 8);
        }
        // Xs: rows 0..63 (256 lanes), tail rows 64..65 (8 lanes)
        gl_lds16(Xt + ((size_t)b * 456 + t0 + sr) * 512 + ci0 + sc16 * 8,
                 Xs + (size_t)(w * 64) * 8);
        if (tid < 8) {
            gl_lds16(Xt + ((size_t)b * 456 + t0 + 64 + (tid >> 2)) * 512 + ci0 + (tid & 3) * 8,
                     Xs + (size_t)256 * 8);
        }
        __syncthreads();   // vmcnt(0) drained here -> LDS valid
        #pragma unroll
        for (int dt = 0; dt < 3; ++dt) {
            short8 af[4], bfr[2];
            #pragma unroll
            for (int mt = 0; mt < 4; ++mt)
                af[mt] = *(const short8*)(As + (size_t)(dt * 128 + wm * 64 + mt * 16 + l15) * 32 + quad * 8);
            #pragma unroll
            for (int nt = 0; nt < 2; ++nt)
                bfr[nt] = *(const short8*)(Xs + (size_t)(wn * 32 + nt * 16 + l15 + dt) * 32 + quad * 8);
            #pragma unroll
            for (int mt = 0; mt < 4; ++mt)
                #pragma unroll
                for (int nt = 0; nt < 2; ++nt)
                    acc[mt][nt] = __builtin_amdgcn_mfma_f32_16x16x32_bf16(af[mt], bfr[nt], acc[mt][nt], 0, 0, 0);
        }
    }
    #pragma unroll
    for (int mt = 0; mt < 4; ++mt) {
        int cob = co0 + wm * 64 + mt * 16 + quad * 4;
        float bv[4];
        #pragma unroll
        for (int r = 0; r < 4; ++r) bv[r] = bias[cob + r];
        #pragma unroll
        for (int nt = 0; nt < 2; ++nt) {
            int t = t0 + wn * 32 + nt * 16 + l15;
            if (t >= 400) continue;
            float v0 = fmaxf(acc[mt][nt][0] + bv[0], 0.f);
            float v1 = fmaxf(acc[mt][nt][1] + bv[1], 0.f);
            float v2 = fmaxf(acc[mt][nt][2] + bv[2], 0.f);
            float v3 = fmaxf(acc[mt][nt][3] + bv[3], 0.f);
            uint2 p;
            p.x = pack2(v0, v1);
            p.y = pack2(v2, v3);
            *(uint2*)(k1c + ((size_t)b * 400 + t) * 1024 + cob) = p;
        }
    }
}

// ---------------- k2 GEMM with K split across 4 waves (800 blocks) ----------------
__global__ __launch_bounds__(256) void gemm_k2_kernel(
        const unsigned short* __restrict__ A, const unsigned short* __restrict__ X,
        const float* __restrict__ bias, unsigned short* __restrict__ out) {
    __shared__ float red[3][64][21];
    const int b = blockIdx.y;
    const int tid = threadIdx.x, lane = tid & 63, w = tid >> 6;
    const int l15 = lane & 15, quad = lane >> 4;
    const int s = blockIdx.x * 16 + l15;          // 25*16 = 400, always valid
    const unsigned short* xb = X + ((size_t)b * 400 + s) * 1024 + quad * 8;
    f32x4 acc[5];
    #pragma unroll
    for (int mt = 0; mt < 5; ++mt) acc[mt] = (f32x4){0.f, 0.f, 0.f, 0.f};
    #pragma unroll
    for (int kk = 0; kk < 8; ++kk) {
        int kc = w * 8 + kk;
        short8 bfr = *(const short8*)(xb + kc * 32);
        #pragma unroll
        for (int mt = 0; mt < 5; ++mt) {
            short8 af = *(const short8*)(A + (size_t)(mt * 16 + l15) * 1024 + kc * 32 + quad * 8);
            acc[mt] = __builtin_amdgcn_mfma_f32_16x16x32_bf16(af, bfr, acc[mt], 0, 0, 0);
        }
    }
    if (w > 0) {
        #pragma unroll
        for (int mt = 0; mt < 5; ++mt)
            #pragma unroll
            for (int r = 0; r < 4; ++r)
                red[w - 1][lane][mt * 4 + r] = acc[mt][r];
    }
    __syncthreads();
    if (w != 0) return;
    #pragma unroll
    for (int wv = 0; wv < 3; ++wv)
        #pragma unroll
        for (int mt = 0; mt < 5; ++mt)
            #pragma unroll
            for (int r = 0; r < 4; ++r)
                acc[mt][r] += red[wv][lane][mt * 4 + r];
    float v[5][4];
    float ss = 0.f;
    #pragma unroll
    for (int mt = 0; mt < 5; ++mt)
        #pragma unroll
        for (int r = 0; r < 4; ++r) {
            float x = acc[mt][r] + bias[mt * 16 + quad * 4 + r];
            v[mt][r] = x;
            ss += x * x;
        }
    ss += __shfl_xor(ss, 16, 64);
    ss += __shfl_xor(ss, 32, 64);
    unsigned short* orow = out + ((size_t)b * 400 + s) * 96;
    #pragma unroll
    for (int mt = 0; mt < 5; ++mt) {
        uint2 p;
        p.x = pack2(v[mt][0], v[mt][1]);
        p.y = pack2(v[mt][2], v[mt][3]);
        *(uint2*)(orow + mt * 16 + quad * 4) = p;
    }
    if (quad == 0) {
        uint4 z0 = {pack2(-0.5f * ss, 1.0f), 0u, 0u, 0u};
        uint4 z1 = {0u, 0u, 0u, 0u};
        *(uint4*)(orow + 80) = z0;
        *(uint4*)(orow + 88) = z1;
    }
}

// ---------------- fused q-path: k3-conv(relu) -> 1x1(relu) -> 1x1 + q2 epilogue --------
// Wave-private chaining: stages chain through LDS with NO barriers (rows are wave-private).
__global__ __launch_bounds__(256) void qpath_fused(
        const unsigned short* __restrict__ A3, const unsigned short* __restrict__ A4,
        const unsigned short* __restrict__ A5, const unsigned short* __restrict__ Xq1,
        const float* __restrict__ bq1, const float* __restrict__ bq2,
        const float* __restrict__ bq3, unsigned short* __restrict__ qT) {
    __shared__ short LA[64 * 168];   // stage-1 out: [t_local][160ch] (pad 168)
    __shared__ short LB[64 * 104];   // stage-2 out: [t_local][96ch]  (pad 104)
    const int b = blockIdx.y;
    const int t0 = blockIdx.x * 64;
    const int tid = threadIdx.x;
    const int lane = tid & 63, w = tid >> 6;
    const int l15 = lane & 15, quad = lane >> 4;
    const int row = w * 16 + l15;          // wave-private local t row
    const int s = t0 + row;                // global t row, always < 1600
    const unsigned short* xb = Xq1 + (size_t)b * 1602 * 96;

    // ---- stage 1 (q1): relu(conv3) -> LA; K = 288 (3 dt x 96 ch), M = 160 ----
    {
        f32x4 acc[10];
        #pragma unroll
        for (int mt = 0; mt < 10; ++mt) acc[mt] = (f32x4){0.f, 0.f, 0.f, 0.f};
        #pragma unroll
        for (int kc = 0; kc < 9; ++kc) {
            const int dt = kc / 3, koff = (kc - dt * 3) * 32;
            short8 bfr = *(const short8*)(xb + (size_t)(s + dt) * 96 + koff + quad * 8);
            #pragma unroll
            for (int mt = 0; mt < 10; ++mt) {
                short8 af = *(const short8*)(A3 + (size_t)(mt * 16 + l15) * 288 + kc * 32 + quad * 8);
                acc[mt] = __builtin_amdgcn_mfma_f32_16x16x32_bf16(af, bfr, acc[mt], 0, 0, 0);
            }
        }
        #pragma unroll
        for (int mt = 0; mt < 10; ++mt) {
            float x0 = fmaxf(acc[mt][0] + bq1[mt * 16 + quad * 4 + 0], 0.f);
            float x1 = fmaxf(acc[mt][1] + bq1[mt * 16 + quad * 4 + 1], 0.f);
            float x2 = fmaxf(acc[mt][2] + bq1[mt * 16 + quad * 4 + 2], 0.f);
            float x3 = fmaxf(acc[mt][3] + bq1[mt * 16 + quad * 4 + 3], 0.f);
            uint2 p;
            p.x = pack2(x0, x1);
            p.y = pack2(x2, x3);
            *(uint2*)(LA + row * 168 + mt * 16 + quad * 4) = p;
        }
    }

    // ---- stage 2 (q2): relu(1x1) -> LB; K = 160 (5 kc), M = 80 (+ zero pad to 96) ----
    {
        f32x4 acc[5];
        #pragma unroll
        for (int mt = 0; mt < 5; ++mt) acc[mt] = (f32x4){0.f, 0.f, 0.f, 0.f};
        #pragma unroll
        for (int kc = 0; kc < 5; ++kc) {
            short8 bfr = *(const short8*)(LA + row * 168 + kc * 32 + quad * 8);
            #pragma unroll
            for (int mt = 0; mt < 5; ++mt) {
                short8 af = *(const short8*)(A4 + (size_t)(mt * 16 + l15) * 160 + kc * 32 + quad * 8);
                acc[mt] = __builtin_amdgcn_mfma_f32_16x16x32_bf16(af, bfr, acc[mt], 0, 0, 0);
            }
        }
        #pragma unroll
        for (int mt = 0; mt < 5; ++mt) {
            float x0 = fmaxf(acc[mt][0] + bq2[mt * 16 + quad * 4 + 0], 0.f);
            float x1 = fmaxf(acc[mt][1] + bq2[mt * 16 + quad * 4 + 1], 0.f);
            float x2 = fmaxf(acc[mt][2] + bq2[mt * 16 + quad * 4 + 2], 0.f);
            float x3 = fmaxf(acc[mt][3] + bq2[mt * 16 + quad * 4 + 3], 0.f);
            uint2 p;
            p.x = pack2(x0, x1);
            p.y = pack2(x2, x3);
            *(uint2*)(LB + row * 104 + mt * 16 + quad * 4) = p;
        }
        uint2 z = {0u, 0u};
        *(uint2*)(LB + row * 104 + 80 + quad * 4) = z;   // ch 80..95 = 0 across quads
    }

    // ---- stage 3 (q3): 1x1, no relu; K = 96 (3 kc), M = 80; q2-epilogue to qT ----
    {
        f32x4 acc[5];
        #pragma unroll
        for (int mt = 0; mt < 5; ++mt) acc[mt] = (f32x4){0.f, 0.f, 0.f, 0.f};
        #pragma unroll
        for (int kc = 0; kc < 3; ++kc) {
            short8 bfr = *(const short8*)(LB + row * 104 + kc * 32 + quad * 8);
            #pragma unroll
            for (int mt = 0; mt < 5; ++mt) {
                short8 af = *(const short8*)(A5 + (size_t)(mt * 16 + l15) * 96 + kc * 32 + quad * 8);
                acc[mt] = __builtin_amdgcn_mfma_f32_16x16x32_bf16(af, bfr, acc[mt], 0, 0, 0);
            }
        }
        float v[5][4];
        float ss = 0.f;
        #pragma unroll
        for (int mt = 0; mt < 5; ++mt)
            #pragma unroll
            for (int r = 0; r < 4; ++r) {
                float x = acc[mt][r] + bq3[mt * 16 + quad * 4 + r];
                v[mt][r] = x;
                ss += x * x;
            }
        ss += __shfl_xor(ss, 16, 64);
        ss += __shfl_xor(ss, 32, 64);
        unsigned short* orow = qT + ((size_t)b * T1_ + s) * 96;
        #pragma unroll
        for (int mt = 0; mt < 5; ++mt) {
            uint2 p;
            p.x = pack2(v[mt][0], v[mt][1]);
            p.y = pack2(v[mt][2], v[mt][3]);
            *(uint2*)(orow + mt * 16 + quad * 4) = p;
        }
        if (quad == 0) {
            uint4 z0 = {pack2(1.0f, -0.5f * ss), 0u, 0u, 0u};
            uint4 z1 = {0u, 0u, 0u, 0u};
            *(uint4*)(orow + 80) = z0;
            *(uint4*)(orow + 88) = z1;
        }
    }
}

// ---------------- qk MFMA -> bf16 logits lgt[b][t1][s] ----------------
// Operand-swapped (round-5): lane owns t1 row; 25 x 8B stores/wave.
__global__ __launch_bounds__(64) void attn_logits_kernel(
        const unsigned short* __restrict__ qT, const unsigned short* __restrict__ kT,
        unsigned short* __restrict__ lgt) {
    const int b = blockIdx.y;
    const int t10 = blockIdx.x * 16;
    const int lane = threadIdx.x;
    const int l15 = lane & 15, quad = lane >> 4;

    // B-operand: 16 q-rows (t1 = t10 + l15)
    const unsigned short* qrow = qT + ((size_t)b * T1_ + t10 + l15) * 96;
    short8 bq[3];
    #pragma unroll
    for (int kc = 0; kc < 3; ++kc)
        bq[kc] = *(const short8*)(qrow + kc * 32 + quad * 8);

    f32x4 acc[25];
    #pragma unroll
    for (int ns = 0; ns < 25; ++ns) acc[ns] = (f32x4){0.f, 0.f, 0.f, 0.f};
    // A-operand: s-rows (s = ns*16 + l15 for fragment load)
    const unsigned short* kbase = kT + (size_t)b * T2_ * 96 + l15 * 96 + quad * 8;
    #pragma unroll
    for (int ns = 0; ns < 25; ++ns) {
        #pragma unroll
        for (int kc = 0; kc < 3; ++kc) {
            short8 ak = *(const short8*)(kbase + ns * 16 * 96 + kc * 32);
            acc[ns] = __builtin_amdgcn_mfma_f32_16x16x32_bf16(ak, bq[kc], acc[ns], 0, 0, 0);
        }
    }
    const float K2T = 2.0f * TEMP;
    unsigned short* orow = lgt + ((size_t)b * T1_ + t10 + l15) * T2_;  // lane-owned t1 row
    #pragma unroll
    for (int ns = 0; ns < 25; ++ns) {
        uint2 p;
        p.x = pack2(K2T * acc[ns][0], K2T * acc[ns][1]);
        p.y = pack2(K2T * acc[ns][2], K2T * acc[ns][3]);
        *(uint2*)(orow + ns * 16 + quad * 4) = p;   // s = ns*16 + quad*4 + [0..3]
    }
}

// ---------------- streaming double-softmax: lgt+prior+mask -> attn, lp ----------------
// 4 waves / block, 1 row / wave. Fully coalesced; 51200 waves.
__global__ __launch_bounds__(256) void softmax_kernel(
        const unsigned short* __restrict__ lgt, const int* __restrict__ mask,
        const float* __restrict__ prior,
        float* __restrict__ attn_out, float* __restrict__ lp_out) {
    const int b = blockIdx.y;
    const int t1 = blockIdx.x * 4 + (threadIdx.x >> 6);
    const int lane = threadIdx.x & 63;
    const unsigned short* lrow = lgt + ((size_t)b * T1_ + t1) * T2_;
    const float* prow = prior + ((size_t)b * T1_ + t1) * T2_;
    const int* mrow = mask + b * T2_;

    float l[7], pe[7], kp[7];
    #pragma unroll
    for (int j = 0; j < 7; ++j) {
        int s = lane + 64 * j;
        bool v = (j < 6) || (lane < 16);
        l[j]  = v ? bf2f(lrow[s]) : -1e30f;
        pe[j] = v ? (prow[s] + 1e-8f) : 1.f;
        kp[j] = (v && !mrow[v ? s : 0]) ? 1.f : 0.f;
    }
    float m = l[0];
    #pragma unroll
    for (int j = 1; j < 7; ++j) m = fmaxf(m, l[j]);
    #pragma unroll
    for (int off = 1; off <= 32; off <<= 1) m = fmaxf(m, __shfl_xor(m, off, 64));
    float e1[7];
    float sum = 0.f;
    #pragma unroll
    for (int j = 0; j < 7; ++j) { float e = __expf(l[j] - m); e1[j] = e; sum += e; }
    #pragma unroll
    for (int off = 1; off <= 32; off <<= 1) sum += __shfl_xor(sum, off, 64);
    const float lse = m + __logf(sum);

    float u[7];
    float sum2 = 0.f;
    #pragma unroll
    for (int j = 0; j < 7; ++j) {
        float uu = e1[j] * pe[j] * kp[j];
        u[j] = uu;
        sum2 += uu;
    }
    #pragma unroll
    for (int off = 1; off <= 32; off <<= 1) sum2 += __shfl_xor(sum2, off, 64);
    const float inv = 1.f / sum2;

    float* lpr = lp_out + ((size_t)b * T1_ + t1) * T2_;
    float* atr = attn_out + ((size_t)b * T1_ + t1) * T2_;
    #pragma unroll
    for (int j = 0; j < 7; ++j) {
        int s = lane + 64 * j;
        bool v = (j < 6) || (lane < 16);
        if (v) {
            lpr[s] = l[j] - lse + __logf(pe[j]);
            atr[s] = u[j] * inv;
        }
    }
}

extern "C" void kernel_launch(void* const* d_in, const int* in_sizes, int n_in,
                              void* d_out, int out_size, void* d_ws, size_t ws_size,
                              hipStream_t stream) {
    const float* queries = (const float*)d_in[0];
    const float* keys    = (const float*)d_in[1];
    const int*   mask    = (const int*)d_in[2];
    const float* prior   = (const float*)d_in[3];
    const float* se      = (const float*)d_in[4];
    const float* Wk1 = (const float*)d_in[5];
    const float* bk1 = (const float*)d_in[6];
    const float* Wk2 = (const float*)d_in[7];
    const float* bk2 = (const float*)d_in[8];
    const float* Wq1 = (const float*)d_in[9];
    const float* bq1 = (const float*)d_in[10];
    const float* Wq2 = (const float*)d_in[11];
    const float* bq2 = (const float*)d_in[12];
    const float* Wq3 = (const float*)d_in[13];
    const float* bq3 = (const float*)d_in[14];
    const float* Wks = (const float*)d_in[15];
    const float* bks = (const float*)d_in[16];
    const float* Wqs = (const float*)d_in[17];
    const float* bqs = (const float*)d_in[18];

    // workspace (float units), peak 14,240,768 fl = 57.0 MB:
    // head: kb 0 | qb 16,384 | Ab1 18,944 | A2 805,376 | A3 846,336 | A4 869,376
    //       A5 875,776 | qT 879,616 | kT 3,337,216 | D = 3,951,616
    // keys: Xk @D (3,735,552) | k1c @D+3,735,552 (6,553,600)
    // q:    Xq1 @D (2,460,672)  [Xq2/Xq3 eliminated by qpath_fused]
    // attn: lgt @D (10,240,000 fl as bf16) overlays dead scratch
    float* ws = (float*)d_ws;
    float* kb = ws;
    float* qb = ws + 16384;
    unsigned short* Ab1 = (unsigned short*)(ws + 18944);
    unsigned short* A2  = (unsigned short*)(ws + 805376);
    unsigned short* A3  = (unsigned short*)(ws + 846336);
    unsigned short* A4  = (unsigned short*)(ws + 869376);
    unsigned short* A5  = (unsigned short*)(ws + 875776);
    unsigned short* qT  = (unsigned short*)(ws + 879616);
    unsigned short* kT  = (unsigned short*)(ws + 3337216);
    const size_t D = 3951616;
    unsigned short* Xk  = (unsigned short*)(ws + D);
    unsigned short* k1c = (unsigned short*)(ws + D + 3735552);
    unsigned short* Xq1 = (unsigned short*)(ws + D);
    unsigned short* lgt = (unsigned short*)(ws + D);

    float* attn_out = (float*)d_out;
    float* lp_out   = attn_out + (size_t)B_ * T1_ * T2_;

    prep_kernel<<<dim3(6798), dim3(256), 0, stream>>>(se, Wks, bks, Wqs, bqs, kb, qb,
                                                      Wk1, Wk2, Wq1, Wq2, Wq3,
                                                      Ab1, A2, A3, A4, A5);
    // keys path
    castXk_kernel<<<dim3(8, 8, 32), dim3(256), 0, stream>>>(keys, kb, Xk);
    conv1k_mfma<<<dim3(7, 8, 32), dim3(256), 0, stream>>>(Ab1, Xk, bk1, k1c);
    gemm_k2_kernel<<<dim3(25, 32), 256, 0, stream>>>(A2, k1c, bk2, kT);
    // query path (fused: q1 -> q2 -> q3 in one kernel, LDS-chained)
    castXq_kernel<<<dim3(25, 32), dim3(256), 0, stream>>>(queries, qb, Xq1);
    qpath_fused<<<dim3(25, 32), dim3(256), 0, stream>>>(A3, A4, A5, Xq1,
                                                        bq1, bq2, bq3, qT);
    // attention: MFMA logits (bf16) then streaming double-softmax
    attn_logits_kernel<<<dim3(100, 32), dim3(64), 0, stream>>>(qT, kT, lgt);
    softmax_kernel<<<dim3(400, 32), dim3(256), 0, stream>>>(lgt, mask, prior, attn_out, lp_out);
}